// Round 8
// baseline (422.343 us; speedup 1.0000x reference)
//
#include <hip/hip_runtime.h>
#include <hip/hip_bf16.h>

// MultiHeadSelfAttentionEinSum2D: B=8,P=4,N=1024,D=384,H=8,PD=48
// prep -> QKV tiled GEMM (Q pre-scaled by 1/sqrt(48)) -> flash attention
// (gload_lds staging, defer-max, XCD swizzle) -> output projection GEMM

#define BP 32
#define NN 1024
#define DD 384
#define HH 8
#define PDIM 48
#define E3 144
#define OO 1152
#define EP 64
#define VROWS 64
#define MTOT (BP * NN)  // 32768

typedef unsigned short u16;
typedef __attribute__((ext_vector_type(8))) short short8;
typedef __attribute__((ext_vector_type(4))) float f32x4;

__device__ __forceinline__ u16 f2bf(float f) {
    union { float f; unsigned int u; } v;
    v.f = f;
    unsigned int u = v.u;
    unsigned int r = u + 0x7FFFu + ((u >> 16) & 1u);  // RNE
    return (u16)(r >> 16);
}

__device__ __forceinline__ u16 f2bf_hw(float f) {
    union { __hip_bfloat16 b; u16 u; } v;
    v.b = __float2bfloat16(f);  // hardware v_cvt (RNE), compiler pairs into cvt_pk
    return v.u;
}

// async global->LDS, 16B per lane. LDS dest: wave-uniform base + lane*16 (linear).
__device__ __forceinline__ void gload16(const u16* g, u16* l) {
    __builtin_amdgcn_global_load_lds(
        (const __attribute__((address_space(1))) void*)g,
        (__attribute__((address_space(3))) void*)l, 16, 0, 0);
}

// ---------------- prep: weights -> bf16 (k-contiguous), x -> bf16 ----------------
__global__ void prep_kernel(const float* __restrict__ x,
                            const float* __restrict__ w_qkv,
                            const float* __restrict__ w_o,
                            u16* __restrict__ Wt, u16* __restrict__ Wot,
                            u16* __restrict__ xb) {
    int stride = gridDim.x * blockDim.x;
    int t0 = blockIdx.x * blockDim.x + threadIdx.x;
    for (int i = t0; i < OO * DD; i += stride) {
        int o = i / DD, d = i - o * DD;
        Wt[i] = f2bf(w_qkv[(size_t)d * OO + o]);
    }
    for (int i = t0; i < DD * DD; i += stride) {
        int dd = i / DD, he = i - dd * DD;
        int h = he / PDIM, e = he - h * PDIM;
        Wot[i] = f2bf(w_o[((size_t)e * HH + h) * DD + dd]);
    }
    for (int i = t0; i < MTOT * DD / 8; i += stride) {
        const float4* xp = reinterpret_cast<const float4*>(x + (size_t)i * 8);
        float4 a0 = xp[0], a1 = xp[1];
        short8 v;
        v[0] = (short)f2bf(a0.x); v[1] = (short)f2bf(a0.y);
        v[2] = (short)f2bf(a0.z); v[3] = (short)f2bf(a0.w);
        v[4] = (short)f2bf(a1.x); v[5] = (short)f2bf(a1.y);
        v[6] = (short)f2bf(a1.z); v[7] = (short)f2bf(a1.w);
        reinterpret_cast<short8*>(xb)[i] = v;
    }
}

// ---- shared GEMM helpers: rows of 64 u16 (8x16B chunks), XOR-swizzled ----
__device__ __forceinline__ void stage_tile(const u16* __restrict__ src, int ld,
                                           u16* lds, int tid) {
#pragma unroll
    for (int i = 0; i < 4; ++i) {
        int idx = i * 256 + tid;
        int row = idx >> 3, p = idx & 7;
        int g = p ^ (row & 7);
        gload16(src + (size_t)row * ld + g * 8, lds + idx * 8);
    }
}
__device__ __forceinline__ short8 lds_frag(const u16* lds, int row, int kk, int lg) {
    int p = (kk * 4 + lg) ^ (row & 7);
    return *reinterpret_cast<const short8*>(lds + row * 64 + p * 8);
}

// ---------------- QKV projection: C[32768x1152] = xb * Wt^T ----------------
__global__ __launch_bounds__(256) void qkv_kernel(
    const u16* __restrict__ xb, const float* __restrict__ b_qkv,
    const u16* __restrict__ Wt,
    u16* __restrict__ q_ws, u16* __restrict__ k_ws, u16* __restrict__ vt_ws) {
    __shared__ alignas(16) u16 Al[128 * 64];
    __shared__ alignas(16) u16 Bl[128 * 64];
    int mt = blockIdx.x, nt = blockIdx.y;
    int tid = threadIdx.x;
    int w = tid >> 6, l = tid & 63, lr = l & 15, lg = l >> 4;
    int wr = w >> 1, wc = w & 1;

    const u16* Abase = xb + (size_t)mt * 128 * DD;
    const u16* Bbase = Wt + (size_t)nt * 128 * DD;

    f32x4 acc[4][4];
#pragma unroll
    for (int mi = 0; mi < 4; ++mi)
#pragma unroll
        for (int ni = 0; ni < 4; ++ni) acc[mi][ni] = (f32x4)(0.f);

#pragma unroll 1
    for (int kt = 0; kt < 6; ++kt) {
        __syncthreads();
        stage_tile(Abase + kt * 64, DD, Al, tid);
        stage_tile(Bbase + kt * 64, DD, Bl, tid);
        __syncthreads();
#pragma unroll
        for (int kk = 0; kk < 2; ++kk) {
            short8 a[4], b[4];
#pragma unroll
            for (int mi = 0; mi < 4; ++mi) a[mi] = lds_frag(Al, wr * 64 + mi * 16 + lr, kk, lg);
#pragma unroll
            for (int ni = 0; ni < 4; ++ni) b[ni] = lds_frag(Bl, wc * 64 + ni * 16 + lr, kk, lg);
#pragma unroll
            for (int mi = 0; mi < 4; ++mi)
#pragma unroll
                for (int ni = 0; ni < 4; ++ni)
                    acc[mi][ni] = __builtin_amdgcn_mfma_f32_16x16x32_bf16(a[mi], b[ni], acc[mi][ni], 0, 0, 0);
        }
    }

    const float inv_scale = 0.14433756729740643f;  // 1/sqrt(48), folded into Q
#pragma unroll
    for (int ni = 0; ni < 4; ++ni) {
        int o = nt * 128 + wc * 64 + ni * 16 + lr;
        int h = o / E3, e3 = o - h * E3;
        float bias = b_qkv[o];
#pragma unroll
        for (int mi = 0; mi < 4; ++mi)
#pragma unroll
            for (int r = 0; r < 4; ++r) {
                int M = mt * 128 + wr * 64 + mi * 16 + lg * 4 + r;
                int bp = M >> 10, nn = M & 1023;
                size_t bh = (size_t)bp * HH + h;
                float val = acc[mi][ni][r] + bias;
                if (e3 < 48) {
                    size_t base = (bh * NN + nn) * EP;
                    q_ws[base + e3] = f2bf(val * inv_scale);
                    if (e3 < 16) q_ws[base + 48 + e3] = 0;
                } else if (e3 < 96) {
                    int c = e3 - 48;
                    size_t base = (bh * NN + nn) * EP;
                    k_ws[base + c] = f2bf(val);
                    if (c < 16) k_ws[base + 48 + c] = 0;
                } else {
                    vt_ws[(bh * VROWS + (e3 - 96)) * NN + nn] = f2bf(val);
                }
            }
    }
}

// ---------------- flash attention v2 ----------------
// 1D grid 2048 (XCD-swizzled), block 256 (4 waves, 32 Q-rows each; QBLK=128)
__global__ __launch_bounds__(256) void attn_kernel(
    const u16* __restrict__ q_ws, const u16* __restrict__ k_ws,
    const u16* __restrict__ vt_ws, u16* __restrict__ wv_ws) {
    int bid = blockIdx.x;
    int wgid = (bid & 7) * 256 + (bid >> 3);  // XCD k owns bph [k*32,(k+1)*32)
    int bph = wgid >> 3, rt = wgid & 7;
    int bp = bph >> 3, hd = bph & 7;
    int tid = threadIdx.x;
    int w = tid >> 6, l = tid & 63, lr = l & 15, lg = l >> 4;

    __shared__ alignas(16) u16 Klds[64 * 64];     // swizzled, gload_lds
    __shared__ alignas(16) u16 Vlds[64 * 64];     // swizzled (rows 48..63 unused)
    __shared__ alignas(16) u16 Plds[4][32][72];   // per-wave, padded

    // Q fragments: wave owns rows rt*128 + w*32 + hh*16 + lr (pre-scaled by 1/sqrt(48))
    short8 aq[2][2];
#pragma unroll
    for (int hh = 0; hh < 2; ++hh) {
        const u16* qrow = q_ws + ((size_t)bph * NN + rt * 128 + w * 32 + hh * 16 + lr) * EP;
        aq[hh][0] = *reinterpret_cast<const short8*>(qrow + lg * 8);
        aq[hh][1] = *reinterpret_cast<const short8*>(qrow + 32 + lg * 8);
    }

    f32x4 accO[2][3];
#pragma unroll
    for (int hh = 0; hh < 2; ++hh)
#pragma unroll
        for (int et = 0; et < 3; ++et) accO[hh][et] = (f32x4)(0.f);
    float mrun[2][4], lrun[2][4];
#pragma unroll
    for (int hh = 0; hh < 2; ++hh)
#pragma unroll
        for (int r = 0; r < 4; ++r) { mrun[hh][r] = -1e30f; lrun[hh][r] = 0.f; }

#pragma unroll 1
    for (int jc = 0; jc < 16; ++jc) {
        // stage K[64][64] and V^T[64][64] via gload_lds, pre-inverse-swizzled source
#pragma unroll
        for (int i = 0; i < 2; ++i) {
            int idx = i * 256 + tid, row = idx >> 3, p = idx & 7;
            int g = p ^ (row & 7);
            gload16(k_ws + ((size_t)bph * NN + jc * 64 + row) * EP + g * 8, Klds + idx * 8);
            gload16(vt_ws + ((size_t)bph * VROWS + row) * NN + jc * 64 + g * 8, Vlds + idx * 8);
        }
        __syncthreads();  // vmcnt(0) drained before barrier -> tiles ready

        // S = Q K^T : 16 MFMA, 8 swizzled ds_read_b128
        f32x4 s[2][4];
#pragma unroll
        for (int hh = 0; hh < 2; ++hh)
#pragma unroll
            for (int ct = 0; ct < 4; ++ct) s[hh][ct] = (f32x4)(0.f);
#pragma unroll
        for (int ct = 0; ct < 4; ++ct)
#pragma unroll
            for (int kk = 0; kk < 2; ++kk) {
                short8 bk = lds_frag(Klds, ct * 16 + lr, kk, lg);
#pragma unroll
                for (int hh = 0; hh < 2; ++hh)
                    s[hh][ct] = __builtin_amdgcn_mfma_f32_16x16x32_bf16(aq[hh][kk], bk, s[hh][ct], 0, 0, 0);
            }

        // tile max per row (row q = hh*16 + lg*4 + r, cols across lr within 16-lane group)
        float pmax[2][4];
        bool stable = true;
#pragma unroll
        for (int hh = 0; hh < 2; ++hh)
#pragma unroll
            for (int r = 0; r < 4; ++r) {
                float m = fmaxf(fmaxf(s[hh][0][r], s[hh][1][r]), fmaxf(s[hh][2][r], s[hh][3][r]));
#pragma unroll
                for (int off = 1; off < 16; off <<= 1) m = fmaxf(m, __shfl_xor(m, off));
                pmax[hh][r] = m;
                stable = stable && (m <= mrun[hh][r] + 8.f);
            }
        // defer-max: only rescale when some row's max grew past threshold (wave-uniform)
        if (!__all(stable)) {
#pragma unroll
            for (int hh = 0; hh < 2; ++hh)
#pragma unroll
                for (int r = 0; r < 4; ++r) {
                    float mnew = fmaxf(mrun[hh][r], pmax[hh][r]);
                    float alpha = __expf(mrun[hh][r] - mnew);
                    mrun[hh][r] = mnew;
                    lrun[hh][r] *= alpha;
#pragma unroll
                    for (int et = 0; et < 3; ++et) accO[hh][et][r] *= alpha;
                }
        }
        // P = exp(S - m), row-sums, P -> LDS (A-layout round trip)
#pragma unroll
        for (int hh = 0; hh < 2; ++hh)
#pragma unroll
            for (int r = 0; r < 4; ++r) {
#pragma unroll
                for (int ct = 0; ct < 4; ++ct) s[hh][ct][r] = __expf(s[hh][ct][r] - mrun[hh][r]);
                float rs = s[hh][0][r] + s[hh][1][r] + s[hh][2][r] + s[hh][3][r];
#pragma unroll
                for (int off = 1; off < 16; off <<= 1) rs += __shfl_xor(rs, off);
                lrun[hh][r] += rs;
            }
#pragma unroll
        for (int hh = 0; hh < 2; ++hh)
#pragma unroll
            for (int ct = 0; ct < 4; ++ct)
#pragma unroll
                for (int r = 0; r < 4; ++r)
                    Plds[w][hh * 16 + lg * 4 + r][ct * 16 + lr] = f2bf_hw(s[hh][ct][r]);

        // O += P V : 12 MFMA (per-wave Plds RAW, compiler inserts lgkmcnt)
#pragma unroll
        for (int kb = 0; kb < 2; ++kb) {
            short8 ap[2];
#pragma unroll
            for (int hh = 0; hh < 2; ++hh)
                ap[hh] = *reinterpret_cast<const short8*>(&Plds[w][hh * 16 + lr][kb * 32 + lg * 8]);
#pragma unroll
            for (int et = 0; et < 3; ++et) {
                short8 bv = lds_frag(Vlds, et * 16 + lr, kb, lg);
#pragma unroll
                for (int hh = 0; hh < 2; ++hh)
                    accO[hh][et] = __builtin_amdgcn_mfma_f32_16x16x32_bf16(ap[hh], bv, accO[hh][et], 0, 0, 0);
            }
        }
        __syncthreads();  // all waves done reading K/V before next stage
    }

    // normalize, write wv in [bp][n][hd*48+e] (k-contiguous for oproj)
#pragma unroll
    for (int hh = 0; hh < 2; ++hh)
#pragma unroll
        for (int et = 0; et < 3; ++et)
#pragma unroll
            for (int r = 0; r < 4; ++r) {
                int nn = rt * 128 + w * 32 + hh * 16 + lg * 4 + r;
                int he = hd * PDIM + et * 16 + lr;
                wv_ws[((size_t)bp * NN + nn) * DD + he] = f2bf(accO[hh][et][r] / lrun[hh][r]);
            }
}

// ---------------- output projection: out[32768x384] = wv * Wot^T + b_o ----------------
__global__ __launch_bounds__(256) void oproj_kernel(
    const u16* __restrict__ wv_ws, const u16* __restrict__ Wot,
    const float* __restrict__ b_o, float* __restrict__ out) {
    __shared__ alignas(16) u16 Al[128 * 64];
    __shared__ alignas(16) u16 Bl[128 * 64];
    int mt = blockIdx.x, nt = blockIdx.y;
    int tid = threadIdx.x;
    int w = tid >> 6, l = tid & 63, lr = l & 15, lg = l >> 4;
    int wr = w >> 1, wc = w & 1;

    const u16* Abase = wv_ws + (size_t)mt * 128 * DD;
    const u16* Bbase = Wot + (size_t)nt * 128 * DD;

    f32x4 acc[4][4];
#pragma unroll
    for (int mi = 0; mi < 4; ++mi)
#pragma unroll
        for (int ni = 0; ni < 4; ++ni) acc[mi][ni] = (f32x4)(0.f);

#pragma unroll 1
    for (int kt = 0; kt < 6; ++kt) {
        __syncthreads();
        stage_tile(Abase + kt * 64, DD, Al, tid);
        stage_tile(Bbase + kt * 64, DD, Bl, tid);
        __syncthreads();
#pragma unroll
        for (int kk = 0; kk < 2; ++kk) {
            short8 a[4], b[4];
#pragma unroll
            for (int mi = 0; mi < 4; ++mi) a[mi] = lds_frag(Al, wr * 64 + mi * 16 + lr, kk, lg);
#pragma unroll
            for (int ni = 0; ni < 4; ++ni) b[ni] = lds_frag(Bl, wc * 64 + ni * 16 + lr, kk, lg);
#pragma unroll
            for (int mi = 0; mi < 4; ++mi)
#pragma unroll
                for (int ni = 0; ni < 4; ++ni)
                    acc[mi][ni] = __builtin_amdgcn_mfma_f32_16x16x32_bf16(a[mi], b[ni], acc[mi][ni], 0, 0, 0);
        }
    }

#pragma unroll
    for (int ni = 0; ni < 4; ++ni) {
        int d = nt * 128 + wc * 64 + ni * 16 + lr;
        float bo = b_o[d];
#pragma unroll
        for (int mi = 0; mi < 4; ++mi)
#pragma unroll
            for (int r = 0; r < 4; ++r) {
                int M = mt * 128 + wr * 64 + mi * 16 + lg * 4 + r;
                out[(size_t)M * DD + d] = acc[mi][ni][r] + bo;
            }
    }
}

extern "C" void kernel_launch(void* const* d_in, const int* in_sizes, int n_in,
                              void* d_out, int out_size, void* d_ws, size_t ws_size,
                              hipStream_t stream) {
    const float* x     = (const float*)d_in[0];
    const float* w_qkv = (const float*)d_in[1];
    const float* b_qkv = (const float*)d_in[2];
    const float* w_o   = (const float*)d_in[3];
    const float* b_o   = (const float*)d_in[4];
    float* out = (float*)d_out;

    char* ws = (char*)d_ws;
    size_t off = 0;
    u16* Wt    = (u16*)(ws + off); off += (size_t)OO * DD * 2;             // 0.88 MB
    u16* Wot   = (u16*)(ws + off); off += (size_t)DD * DD * 2;             // 0.29 MB
    u16* q_ws  = (u16*)(ws + off); off += (size_t)BP * HH * NN * EP * 2;   // 33.5 MB
    u16* k_ws  = (u16*)(ws + off); off += (size_t)BP * HH * NN * EP * 2;   // 33.5 MB
    u16* vt_ws = (u16*)(ws + off); off += (size_t)BP * HH * VROWS * NN * 2; // 33.5 MB
    u16* wv_ws = (u16*)(ws + off); off += (size_t)BP * NN * DD * 2;        // 25.2 MB
    u16* xb    = wv_ws;  // alias: xb dead before attn writes wv_ws
    (void)ws_size;

    prep_kernel<<<2048, 256, 0, stream>>>(x, w_qkv, w_o, Wt, Wot, xb);
    qkv_kernel<<<dim3(256, 9), 256, 0, stream>>>(xb, b_qkv, Wt, q_ws, k_ws, vt_ws);
    attn_kernel<<<2048, 256, 0, stream>>>(q_ws, k_ws, vt_ws, wv_ws);
    oproj_kernel<<<dim3(256, 3), 256, 0, stream>>>(wv_ws, Wot, b_o, out);
}